// Round 6
// baseline (146.099 us; speedup 1.0000x reference)
//
#include <hip/hip_runtime.h>
#include <hip/hip_bf16.h>

#define B_SZ   8192
#define NPATCH 196
#define FEAT   784     // true K
#define KP     832     // K padded to BK=64 (13 iters, no bounds checks)
#define IMGPX  784
#define NCLS   10
#define NALL   794     // IMGPX + NCLS
#define NP     896     // N padded (rows 794..895 zeroed)
#define NKIT   13      // KP/64

typedef __attribute__((ext_vector_type(8))) short bf16x8;
typedef __attribute__((ext_vector_type(4))) float fx4;

__device__ inline unsigned short f2bf(float f){
    union { __hip_bfloat16 h; unsigned short u; } cv;
    cv.h = __float2bfloat16(f);
    return cv.u;
}

// ---------------- fused: global max (blocks 0..1023) + weight->bf16 pad (1024..1751)
// maxslot holds raw float bits via SIGNED int atomicMax (true max always > 0;
// 0xAA poison is negative as int) -> no memset dispatch needed.
__global__ __launch_bounds__(256) void k_maxprep(const float* __restrict__ x,
                                                 const float* __restrict__ Wr,
                                                 const float* __restrict__ Wc,
                                                 const float* __restrict__ ansatz,
                                                 int* __restrict__ maxslot,
                                                 unsigned short* __restrict__ Wall,
                                                 float* __restrict__ trig){
    if (blockIdx.x < 1024){
        const int n4 = (B_SZ * IMGPX) / 4;
        float m = -3.0e38f;
        for (int i = blockIdx.x * 256 + threadIdx.x; i < n4; i += 1024 * 256){
            float4 v = ((const float4*)x)[i];
            m = fmaxf(m, fmaxf(fmaxf(v.x, v.y), fmaxf(v.z, v.w)));
        }
        #pragma unroll
        for (int off = 32; off > 0; off >>= 1)
            m = fmaxf(m, __shfl_down(m, off, 64));
        __shared__ float sm[4];
        int lane = threadIdx.x & 63, wv = threadIdx.x >> 6;
        if (lane == 0) sm[wv] = m;
        __syncthreads();
        if (threadIdx.x == 0){
            m = fmaxf(fmaxf(sm[0], sm[1]), fmaxf(sm[2], sm[3]));
            atomicMax(maxslot, (int)__float_as_uint(m));
        }
        return;
    }
    if (blockIdx.x == 1024 && threadIdx.x < 8){
        float p = ansatz[threadIdx.x];
        trig[threadIdx.x]     = cosf(0.5f * p);
        trig[8 + threadIdx.x] = sinf(0.5f * p);
    }
    int e4  = (blockIdx.x - 1024) * 256 + threadIdx.x;
    if (e4 >= NP * (KP / 4)) return;
    int row = e4 / (KP / 4);             // 208 ushort4 per row
    int c4  = e4 - row * (KP / 4);
    float4 v = {0.f, 0.f, 0.f, 0.f};
    if (c4 < 196){
        int col = c4 * 4;
        if (row < IMGPX)       v = *(const float4*)(Wr + row * FEAT + col);
        else if (row < NALL)   v = *(const float4*)(Wc + (row - IMGPX) * FEAT + col);
    }
    ushort4 o;
    o.x = f2bf(v.x); o.y = f2bf(v.y); o.z = f2bf(v.z); o.w = f2bf(v.w);
    ((ushort4*)Wall)[e4] = o;
}

// ---------------- 4-qubit circuit per patch, float2-packed state.
__global__ __launch_bounds__(256) void k_sim(const float* __restrict__ x,
                                             const int* __restrict__ maxslot,
                                             const float* __restrict__ trig,
                                             unsigned short* __restrict__ flatb){
    int idx = blockIdx.x * 256 + threadIdx.x;
    if (idx >= B_SZ * NPATCH) return;
    int b  = idx / NPATCH;
    int p  = idx - b * NPATCH;
    int pi = p / 14;
    int pj = p - pi * 14;
    const float* base = x + b * IMGPX + pi * 2 * 28 + pj * 2;
    float2 r0 = *(const float2*)(base);
    float2 r1 = *(const float2*)(base + 28);
    float inv = 1.0f / __uint_as_float((unsigned)*maxslot);
    float th[4] = { r0.x * inv, r0.y * inv, r1.x * inv, r1.y * inv };
    float cw[4], sw[4];
    #pragma unroll
    for (int w = 0; w < 4; ++w) __sincosf(0.5f * th[w], &sw[w], &cw[w]);

    float2 s2[8];
    {
        float q00 = cw[0] * cw[1], q01 = cw[0] * sw[1];
        float q10 = sw[0] * cw[1], q11 = sw[0] * sw[1];
        float pk[8];
        pk[0] = q00 * cw[2]; pk[1] = q00 * sw[2];
        pk[2] = q01 * cw[2]; pk[3] = q01 * sw[2];
        pk[4] = q10 * cw[2]; pk[5] = q10 * sw[2];
        pk[6] = q11 * cw[2]; pk[7] = q11 * sw[2];
        #pragma unroll
        for (int k = 0; k < 8; ++k)
            s2[k] = make_float2(pk[k] * cw[3], pk[k] * sw[3]);
    }

    #pragma unroll
    for (int l = 0; l < 2; ++l){
        #pragma unroll
        for (int w = 0; w < 3; ++w){
            float cc = trig[l * 4 + w], ss = trig[8 + l * 4 + w];
            int m = 4 >> w;
            #pragma unroll
            for (int k = 0; k < 8; ++k){
                if (!(k & m)){
                    float2 a0 = s2[k], a1 = s2[k + m];
                    s2[k].x     = cc * a0.x - ss * a1.x;
                    s2[k].y     = cc * a0.y - ss * a1.y;
                    s2[k + m].x = ss * a0.x + cc * a1.x;
                    s2[k + m].y = ss * a0.y + cc * a1.y;
                }
            }
        }
        {
            float cc = trig[l * 4 + 3], ss = trig[8 + l * 4 + 3];
            #pragma unroll
            for (int k = 0; k < 8; ++k){
                float2 v = s2[k];
                s2[k].x = cc * v.x - ss * v.y;
                s2[k].y = ss * v.x + cc * v.y;
            }
        }
        { float2 t = s2[4]; s2[4] = s2[6]; s2[6] = t;
          t = s2[5]; s2[5] = s2[7]; s2[7] = t; }
        { float2 t = s2[2]; s2[2] = s2[3]; s2[3] = t;
          t = s2[6]; s2[6] = s2[7]; s2[7] = t; }
        #pragma unroll
        for (int k = 1; k < 8; k += 2) s2[k] = make_float2(s2[k].y, s2[k].x);
        #pragma unroll
        for (int k = 0; k < 4; ++k){
            float t = s2[k].y; s2[k].y = s2[k + 4].y; s2[k + 4].y = t;
        }
    }

    float t[8], d[8];
    #pragma unroll
    for (int k = 0; k < 8; ++k){
        float px = s2[k].x * s2[k].x, py = s2[k].y * s2[k].y;
        t[k] = px + py; d[k] = px - py;
    }
    float f0 = (t[0] + t[1] + t[2] + t[3]) - (t[4] + t[5] + t[6] + t[7]);
    float f1 = (t[0] + t[1] + t[4] + t[5]) - (t[2] + t[3] + t[6] + t[7]);
    float f2 = (t[0] + t[2] + t[4] + t[6]) - (t[1] + t[3] + t[5] + t[7]);
    float f3 =  d[0] + d[1] + d[2] + d[3] + d[4] + d[5] + d[6] + d[7];

    ushort4 o; o.x = f2bf(f0); o.y = f2bf(f1); o.z = f2bf(f2); o.w = f2bf(f3);
    ((ushort4*)(flatb + (size_t)b * KP))[p] = o;
    if (p < 12){                                 // zero K-pad cols 784..831
        ushort4 z = {0, 0, 0, 0};
        ((ushort4*)(flatb + (size_t)b * KP + FEAT))[p] = z;
    }
}

// ---------------- 128x128 bf16 MFMA GEMM, BK=64.
// A: double-buffered global_load_lds (XOR-swizzled), barrier-coupled.
// B: direct global->VGPR loads (Wall is 1.5 MB, L2-resident; fragment pattern is
//    16 rows x 64 B contiguous per instruction) -- no LDS, no barrier coupling,
//    loads pipeline inside the iteration under compiler vmcnt.
// LDS 32 KB + 5 KB -> 3 blocks/CU (was 2).  grid.x=bm: same-A blocks share an XCD.
// bn==6 tile owns logit cols 784..793 -> fused log_softmax via LDS.
__global__ __launch_bounds__(256) void k_gemm(const unsigned short* __restrict__ A,
                                              const unsigned short* __restrict__ Wall,
                                              const float* __restrict__ br,
                                              const float* __restrict__ bc,
                                              float* __restrict__ recon,
                                              float* __restrict__ outls){
    __shared__ unsigned short As[2][128][64];    // 2 x 16 KB, unpadded
    __shared__ float sLg[128][NCLS];

    const int t = threadIdx.x;
    const int wv = t >> 6, lane = t & 63;
    const int r = lane & 15, q = lane >> 4;
    const int mb = (wv >> 1) * 64, nb = (wv & 1) * 64;
    const int bm = blockIdx.x, bn = blockIdx.y;

    // A staging: 16 wave-issues of 1 KB (8 rows x 64 bf16); lin = s*4+wv, s=0..3.
    // LDS slot (row,cs) holds global chunk cs ^ (row&7)  (XOR swizzle).
    const unsigned short* gptr[4];
    int lofs[4];
    #pragma unroll
    for (int s = 0; s < 4; ++s){
        int lin = s * 4 + wv;
        int rb  = lin * 8;
        int row = rb + (lane >> 3);
        int kc  = (((lane & 7) ^ (lane >> 3))) * 8;
        gptr[s] = A + (size_t)(bm * 128 + row) * KP + kc;
        lofs[s] = rb * 64;
    }
    // B base: row (bn*128 + nb + j*16 + r), col k0 + h*32 + q*8
    const unsigned short* bbase = Wall + (size_t)(bn * 128 + nb + r) * KP + q * 8;

    fx4 acc[4][4] = {};

    // prologue: stage A tile 0 into buffer 0
    #pragma unroll
    for (int s = 0; s < 4; ++s){
        __builtin_amdgcn_global_load_lds(
            (const __attribute__((address_space(1))) unsigned int*)gptr[s],
            (__attribute__((address_space(3))) unsigned int*)(&As[0][0][0] + lofs[s]),
            16, 0, 0);
        gptr[s] += 64;
    }

    for (int it = 0; it < NKIT; ++it){
        const int cur = it & 1, nxt = cur ^ 1;
        const int k0 = it * 64;
        __syncthreads();      // drains A-prefetch issued one compute-phase ago
        if (it + 1 < NKIT){
            #pragma unroll
            for (int s = 0; s < 4; ++s){
                __builtin_amdgcn_global_load_lds(
                    (const __attribute__((address_space(1))) unsigned int*)gptr[s],
                    (__attribute__((address_space(3))) unsigned int*)(&As[nxt][0][0] + lofs[s]),
                    16, 0, 0);
                gptr[s] += 64;
            }
        }
        #pragma unroll
        for (int h = 0; h < 2; ++h){
            bf16x8 bf[4], af[4];
            #pragma unroll
            for (int j = 0; j < 4; ++j)
                bf[j] = *(const bf16x8*)(bbase + (size_t)(j * 16) * KP + k0 + h * 32);
            #pragma unroll
            for (int i = 0; i < 4; ++i){
                int cs = (h * 4 + q) ^ (r & 7);        // de-swizzle
                af[i] = *(const bf16x8*)&As[cur][mb + i * 16 + r][cs * 8];
            }
            #pragma unroll
            for (int i = 0; i < 4; ++i)
                #pragma unroll
                for (int j = 0; j < 4; ++j)
                    acc[i][j] = __builtin_amdgcn_mfma_f32_16x16x32_bf16(af[i], bf[j], acc[i][j], 0, 0, 0);
        }
    }

    // C/D layout: col = lane&15 (n), row = (lane>>4)*4 + reg (m)
    #pragma unroll
    for (int i = 0; i < 4; ++i){
        int ml = mb + i * 16 + q * 4;
        int m  = bm * 128 + ml;
        #pragma unroll
        for (int j = 0; j < 4; ++j){
            int n = bn * 128 + nb + j * 16 + r;
            if (n < IMGPX){
                float bias = br[n];
                #pragma unroll
                for (int v = 0; v < 4; ++v)
                    recon[(size_t)(m + v) * IMGPX + n] = acc[i][j][v] + bias;
            } else if (n < NALL){
                float bias = bc[n - IMGPX];
                #pragma unroll
                for (int v = 0; v < 4; ++v)
                    sLg[ml + v][n - IMGPX] = acc[i][j][v] + bias;
            }
        }
    }
    if (bn == 6){
        __syncthreads();
        if (t < 128){
            float v[NCLS];
            float mx = -3.0e38f;
            #pragma unroll
            for (int c = 0; c < NCLS; ++c){ v[c] = sLg[t][c]; mx = fmaxf(mx, v[c]); }
            float s = 0.f;
            #pragma unroll
            for (int c = 0; c < NCLS; ++c) s += expf(v[c] - mx);
            float lse = mx + logf(s);
            size_t rowo = (size_t)(bm * 128 + t) * NCLS;
            #pragma unroll
            for (int c = 0; c < NCLS; ++c) outls[rowo + c] = v[c] - lse;
        }
    }
}

extern "C" void kernel_launch(void* const* d_in, const int* in_sizes, int n_in,
                              void* d_out, int out_size, void* d_ws, size_t ws_size,
                              hipStream_t stream){
    const float* x      = (const float*)d_in[0];
    const float* ansatz = (const float*)d_in[1];
    const float* Wc     = (const float*)d_in[2];
    const float* bc     = (const float*)d_in[3];
    const float* Wr     = (const float*)d_in[4];
    const float* br     = (const float*)d_in[5];
    float* out = (float*)d_out;                      // [0,81920): log_softmax; rest: recon

    unsigned char* ws = (unsigned char*)d_ws;
    int*            maxslot = (int*)ws;                               // 4 B (poison-safe)
    float*          trig    = (float*)(ws + 64);                      // 16 f32
    unsigned short* flatb   = (unsigned short*)(ws + 4096);           // 8192 x 832 bf16 = 13.6 MB
    unsigned short* Wall    = (unsigned short*)(ws + 4096 + (size_t)B_SZ * KP * 2); // 896 x 832 bf16

    k_maxprep<<<1752, 256, 0, stream>>>(x, Wr, Wc, ansatz, maxslot, Wall, trig);
    k_sim<<<(B_SZ * NPATCH + 255) / 256, 256, 0, stream>>>(x, maxslot, trig, flatb);
    dim3 g(64, 7);                                   // bm fastest -> XCD-local A reuse
    k_gemm<<<g, 256, 0, stream>>>(flatb, Wall, br, bc, out + B_SZ * NCLS, out);
}

// Round 7
// 129.490 us; speedup vs baseline: 1.1283x; 1.1283x over previous
//
#include <hip/hip_runtime.h>
#include <hip/hip_bf16.h>

#define B_SZ   8192
#define NPATCH 196
#define FEAT   784     // true K
#define KP     832     // K padded to BK=64 (13 iters, no bounds checks)
#define IMGPX  784
#define NCLS   10
#define NALL   794     // IMGPX + NCLS
#define NP     896     // N padded to 7 x 128 tiles (rows 794..895 zeroed)
#define NKIT   13      // KP/64

typedef __attribute__((ext_vector_type(8))) short bf16x8;
typedef __attribute__((ext_vector_type(4))) float fx4;

__device__ inline unsigned short f2bf(float f){
    union { __hip_bfloat16 h; unsigned short u; } cv;
    cv.h = __float2bfloat16(f);
    return cv.u;
}

// ---------------- fused: global max (blocks 0..1023) + weight->bf16 pad (1024..1751)
// maxslot holds raw float bits via SIGNED int atomicMax (true max always > 0;
// 0xAA poison is negative as int) -> no memset dispatch needed.
__global__ __launch_bounds__(256) void k_maxprep(const float* __restrict__ x,
                                                 const float* __restrict__ Wr,
                                                 const float* __restrict__ Wc,
                                                 const float* __restrict__ ansatz,
                                                 int* __restrict__ maxslot,
                                                 unsigned short* __restrict__ Wall,
                                                 float* __restrict__ trig){
    if (blockIdx.x < 1024){
        const int n4 = (B_SZ * IMGPX) / 4;
        float m = -3.0e38f;
        for (int i = blockIdx.x * 256 + threadIdx.x; i < n4; i += 1024 * 256){
            float4 v = ((const float4*)x)[i];
            m = fmaxf(m, fmaxf(fmaxf(v.x, v.y), fmaxf(v.z, v.w)));
        }
        #pragma unroll
        for (int off = 32; off > 0; off >>= 1)
            m = fmaxf(m, __shfl_down(m, off, 64));
        __shared__ float sm[4];
        int lane = threadIdx.x & 63, wv = threadIdx.x >> 6;
        if (lane == 0) sm[wv] = m;
        __syncthreads();
        if (threadIdx.x == 0){
            m = fmaxf(fmaxf(sm[0], sm[1]), fmaxf(sm[2], sm[3]));
            atomicMax(maxslot, (int)__float_as_uint(m));
        }
        return;
    }
    if (blockIdx.x == 1024 && threadIdx.x < 8){
        float p = ansatz[threadIdx.x];
        trig[threadIdx.x]     = cosf(0.5f * p);
        trig[8 + threadIdx.x] = sinf(0.5f * p);
    }
    int e4  = (blockIdx.x - 1024) * 256 + threadIdx.x;
    if (e4 >= NP * (KP / 4)) return;
    int row = e4 / (KP / 4);             // 208 ushort4 per row
    int c4  = e4 - row * (KP / 4);
    float4 v = {0.f, 0.f, 0.f, 0.f};
    if (c4 < 196){
        int col = c4 * 4;
        if (row < IMGPX)       v = *(const float4*)(Wr + row * FEAT + col);
        else if (row < NALL)   v = *(const float4*)(Wc + (row - IMGPX) * FEAT + col);
    }
    ushort4 o;
    o.x = f2bf(v.x); o.y = f2bf(v.y); o.z = f2bf(v.z); o.w = f2bf(v.w);
    ((ushort4*)Wall)[e4] = o;
}

// ---------------- 4-qubit circuit per patch, float2-packed state.
__global__ __launch_bounds__(256) void k_sim(const float* __restrict__ x,
                                             const int* __restrict__ maxslot,
                                             const float* __restrict__ trig,
                                             unsigned short* __restrict__ flatb){
    int idx = blockIdx.x * 256 + threadIdx.x;
    if (idx >= B_SZ * NPATCH) return;
    int b  = idx / NPATCH;
    int p  = idx - b * NPATCH;
    int pi = p / 14;
    int pj = p - pi * 14;
    const float* base = x + b * IMGPX + pi * 2 * 28 + pj * 2;
    float2 r0 = *(const float2*)(base);
    float2 r1 = *(const float2*)(base + 28);
    float inv = 1.0f / __uint_as_float((unsigned)*maxslot);
    float th[4] = { r0.x * inv, r0.y * inv, r1.x * inv, r1.y * inv };
    float cw[4], sw[4];
    #pragma unroll
    for (int w = 0; w < 4; ++w) __sincosf(0.5f * th[w], &sw[w], &cw[w]);

    float2 s2[8];
    {
        float q00 = cw[0] * cw[1], q01 = cw[0] * sw[1];
        float q10 = sw[0] * cw[1], q11 = sw[0] * sw[1];
        float pk[8];
        pk[0] = q00 * cw[2]; pk[1] = q00 * sw[2];
        pk[2] = q01 * cw[2]; pk[3] = q01 * sw[2];
        pk[4] = q10 * cw[2]; pk[5] = q10 * sw[2];
        pk[6] = q11 * cw[2]; pk[7] = q11 * sw[2];
        #pragma unroll
        for (int k = 0; k < 8; ++k)
            s2[k] = make_float2(pk[k] * cw[3], pk[k] * sw[3]);
    }

    #pragma unroll
    for (int l = 0; l < 2; ++l){
        #pragma unroll
        for (int w = 0; w < 3; ++w){
            float cc = trig[l * 4 + w], ss = trig[8 + l * 4 + w];
            int m = 4 >> w;
            #pragma unroll
            for (int k = 0; k < 8; ++k){
                if (!(k & m)){
                    float2 a0 = s2[k], a1 = s2[k + m];
                    s2[k].x     = cc * a0.x - ss * a1.x;
                    s2[k].y     = cc * a0.y - ss * a1.y;
                    s2[k + m].x = ss * a0.x + cc * a1.x;
                    s2[k + m].y = ss * a0.y + cc * a1.y;
                }
            }
        }
        {
            float cc = trig[l * 4 + 3], ss = trig[8 + l * 4 + 3];
            #pragma unroll
            for (int k = 0; k < 8; ++k){
                float2 v = s2[k];
                s2[k].x = cc * v.x - ss * v.y;
                s2[k].y = ss * v.x + cc * v.y;
            }
        }
        { float2 t = s2[4]; s2[4] = s2[6]; s2[6] = t;
          t = s2[5]; s2[5] = s2[7]; s2[7] = t; }
        { float2 t = s2[2]; s2[2] = s2[3]; s2[3] = t;
          t = s2[6]; s2[6] = s2[7]; s2[7] = t; }
        #pragma unroll
        for (int k = 1; k < 8; k += 2) s2[k] = make_float2(s2[k].y, s2[k].x);
        #pragma unroll
        for (int k = 0; k < 4; ++k){
            float t = s2[k].y; s2[k].y = s2[k + 4].y; s2[k + 4].y = t;
        }
    }

    float t[8], d[8];
    #pragma unroll
    for (int k = 0; k < 8; ++k){
        float px = s2[k].x * s2[k].x, py = s2[k].y * s2[k].y;
        t[k] = px + py; d[k] = px - py;
    }
    float f0 = (t[0] + t[1] + t[2] + t[3]) - (t[4] + t[5] + t[6] + t[7]);
    float f1 = (t[0] + t[1] + t[4] + t[5]) - (t[2] + t[3] + t[6] + t[7]);
    float f2 = (t[0] + t[2] + t[4] + t[6]) - (t[1] + t[3] + t[5] + t[7]);
    float f3 =  d[0] + d[1] + d[2] + d[3] + d[4] + d[5] + d[6] + d[7];

    ushort4 o; o.x = f2bf(f0); o.y = f2bf(f1); o.z = f2bf(f2); o.w = f2bf(f3);
    ((ushort4*)(flatb + (size_t)b * KP))[p] = o;
    if (p < 12){                                 // zero K-pad cols 784..831
        ushort4 z = {0, 0, 0, 0};
        ((ushort4*)(flatb + (size_t)b * KP + FEAT))[p] = z;
    }
}

// ---------------- 128x128 bf16 MFMA GEMM, BK=64, DOUBLE-BUFFERED global_load_lds.
// Prefetch for iter k+1 issued right after the barrier publishing iter k's tile:
// MFMA+ds_read of iter k overlaps the staging latency; the next barrier's vmcnt
// drain finds the loads (nearly) complete.  [R6's direct-global B regressed:
// un-staged B puts L2 latency on the critical path — keep both tiles in LDS.]
// XOR-swizzled LDS chunks; grid.x=bm so same-A blocks share an XCD L2.
// bn==6 tile owns logit cols 784..793 -> fused log_softmax via LDS.
__global__ __launch_bounds__(256) void k_gemm(const unsigned short* __restrict__ A,
                                              const unsigned short* __restrict__ Wall,
                                              const float* __restrict__ br,
                                              const float* __restrict__ bc,
                                              float* __restrict__ recon,
                                              float* __restrict__ outls){
    __shared__ unsigned short As[2][128][64];    // 2 x 16 KB, unpadded (global_load_lds)
    __shared__ unsigned short Bs[2][128][64];    // 2 x 16 KB
    __shared__ float sLg[128][NCLS];

    const int t = threadIdx.x;
    const int wv = t >> 6, lane = t & 63;
    const int r = lane & 15, q = lane >> 4;
    const int mb = (wv >> 1) * 64, nb = (wv & 1) * 64;
    const int bm = blockIdx.x, bn = blockIdx.y;

    // staging: 32 wave-issues of 1 KB (8 rows x 64 bf16); lin = s*4+wv.
    // HW writes lane -> base + lane*16: row rb+(lane>>3), chunk lane&7.
    // Source global chunk (lane&7)^(lane>>3): LDS slot (row,cs) = global chunk cs^(row&7).
    const unsigned short* gptr[8];
    int lofs[8];
    #pragma unroll
    for (int s = 0; s < 8; ++s){
        int lin = s * 4 + wv;
        int isB = lin >> 4;
        int rb  = (lin & 15) * 8;
        int row = rb + (lane >> 3);
        int kc  = (((lane & 7) ^ (lane >> 3))) * 8;
        gptr[s] = (isB ? Wall + (size_t)(bn * 128 + row) * KP
                       : A    + (size_t)(bm * 128 + row) * KP) + kc;
        lofs[s] = rb * 64;
        if (isB) lofs[s] |= 0x40000000;
    }

    fx4 acc[4][4] = {};

    // prologue: stage tile 0 into buffer 0
    #pragma unroll
    for (int s = 0; s < 8; ++s){
        unsigned short* lp = (lofs[s] & 0x40000000) ? &Bs[0][0][0] + (lofs[s] & 0xFFFF)
                                                    : &As[0][0][0] + (lofs[s] & 0xFFFF);
        __builtin_amdgcn_global_load_lds(
            (const __attribute__((address_space(1))) unsigned int*)gptr[s],
            (__attribute__((address_space(3))) unsigned int*)lp, 16, 0, 0);
        gptr[s] += 64;
    }

    for (int it = 0; it < NKIT; ++it){
        const int cur = it & 1, nxt = cur ^ 1;
        __syncthreads();      // publishes buf[cur]; also fences last reads of buf[nxt]
        if (it + 1 < NKIT){   // prefetch tile it+1 into buf[nxt]; overlaps compute below
            #pragma unroll
            for (int s = 0; s < 8; ++s){
                unsigned short* lp = (lofs[s] & 0x40000000)
                    ? &Bs[nxt][0][0] + (lofs[s] & 0xFFFF)
                    : &As[nxt][0][0] + (lofs[s] & 0xFFFF);
                __builtin_amdgcn_global_load_lds(
                    (const __attribute__((address_space(1))) unsigned int*)gptr[s],
                    (__attribute__((address_space(3))) unsigned int*)lp, 16, 0, 0);
                gptr[s] += 64;
            }
        }
        bf16x8 af[4][2], bf[4][2];
        #pragma unroll
        for (int i = 0; i < 4; ++i)
            #pragma unroll
            for (int h = 0; h < 2; ++h){
                int cs = (h * 4 + q) ^ (r & 7);        // de-swizzle
                af[i][h] = *(const bf16x8*)&As[cur][mb + i * 16 + r][cs * 8];
            }
        #pragma unroll
        for (int j = 0; j < 4; ++j)
            #pragma unroll
            for (int h = 0; h < 2; ++h){
                int cs = (h * 4 + q) ^ (r & 7);
                bf[j][h] = *(const bf16x8*)&Bs[cur][nb + j * 16 + r][cs * 8];
            }
        #pragma unroll
        for (int h = 0; h < 2; ++h)
            #pragma unroll
            for (int i = 0; i < 4; ++i)
                #pragma unroll
                for (int j = 0; j < 4; ++j)
                    acc[i][j] = __builtin_amdgcn_mfma_f32_16x16x32_bf16(af[i][h], bf[j][h], acc[i][j], 0, 0, 0);
    }
    __syncthreads();

    // C/D layout: col = lane&15 (n), row = (lane>>4)*4 + reg (m)
    #pragma unroll
    for (int i = 0; i < 4; ++i){
        int ml = mb + i * 16 + q * 4;
        int m  = bm * 128 + ml;
        #pragma unroll
        for (int j = 0; j < 4; ++j){
            int n = bn * 128 + nb + j * 16 + r;
            if (n < IMGPX){
                float bias = br[n];
                #pragma unroll
                for (int v = 0; v < 4; ++v)
                    recon[(size_t)(m + v) * IMGPX + n] = acc[i][j][v] + bias;
            } else if (n < NALL){
                float bias = bc[n - IMGPX];
                #pragma unroll
                for (int v = 0; v < 4; ++v)
                    sLg[ml + v][n - IMGPX] = acc[i][j][v] + bias;
            }
        }
    }
    if (bn == 6){
        __syncthreads();
        if (t < 128){
            float v[NCLS];
            float mx = -3.0e38f;
            #pragma unroll
            for (int c = 0; c < NCLS; ++c){ v[c] = sLg[t][c]; mx = fmaxf(mx, v[c]); }
            float s = 0.f;
            #pragma unroll
            for (int c = 0; c < NCLS; ++c) s += expf(v[c] - mx);
            float lse = mx + logf(s);
            size_t rowo = (size_t)(bm * 128 + t) * NCLS;
            #pragma unroll
            for (int c = 0; c < NCLS; ++c) outls[rowo + c] = v[c] - lse;
        }
    }
}

extern "C" void kernel_launch(void* const* d_in, const int* in_sizes, int n_in,
                              void* d_out, int out_size, void* d_ws, size_t ws_size,
                              hipStream_t stream){
    const float* x      = (const float*)d_in[0];
    const float* ansatz = (const float*)d_in[1];
    const float* Wc     = (const float*)d_in[2];
    const float* bc     = (const float*)d_in[3];
    const float* Wr     = (const float*)d_in[4];
    const float* br     = (const float*)d_in[5];
    float* out = (float*)d_out;                      // [0,81920): log_softmax; rest: recon

    unsigned char* ws = (unsigned char*)d_ws;
    int*            maxslot = (int*)ws;                               // 4 B (poison-safe)
    float*          trig    = (float*)(ws + 64);                      // 16 f32
    unsigned short* flatb   = (unsigned short*)(ws + 4096);           // 8192 x 832 bf16 = 13.6 MB
    unsigned short* Wall    = (unsigned short*)(ws + 4096 + (size_t)B_SZ * KP * 2); // 896 x 832 bf16

    k_maxprep<<<1752, 256, 0, stream>>>(x, Wr, Wc, ansatz, maxslot, Wall, trig);
    k_sim<<<(B_SZ * NPATCH + 255) / 256, 256, 0, stream>>>(x, maxslot, trig, flatb);
    dim3 g(64, 7);                                   // bm fastest -> XCD-local A reuse
    k_gemm<<<g, 256, 0, stream>>>(flatb, Wall, br, bc, out + B_SZ * NCLS, out);
}